// Round 10
// baseline (2241.510 us; speedup 1.0000x reference)
//
#include <hip/hip_runtime.h>
#include <hip/hip_bf16.h>
#include <float.h>

#define OUT_CODES_OFF (33554432UL)            // 32768*1024
#define OUT_LOSS_OFF  (34603008UL)            // + 32768*32
#define TAU 1e-5f
#define INV_N (1.0f/33554432.0f)

typedef __attribute__((ext_vector_type(8))) short s16x8;
typedef __attribute__((ext_vector_type(4))) float f32x4;

__device__ __forceinline__ unsigned short bf16r(float x) {
    unsigned int u = __float_as_uint(x);
    unsigned int r = (u + 0x7FFFu + ((u >> 16) & 1u)) >> 16;
    return (unsigned short)r;
}
__device__ __forceinline__ float bf16f(unsigned short h) {
    return __uint_as_float(((unsigned int)h) << 16);
}
// truncation split: x = hi + lo with hi = trunc-bf16(x), lo = rnd-bf16(x - hi)
__device__ __forceinline__ void split8r(float4 v0, float4 v1, s16x8& h, s16x8& l) {
    float xs[8] = {v0.x, v0.y, v0.z, v0.w, v1.x, v1.y, v1.z, v1.w};
    #pragma unroll
    for (int e = 0; e < 8; ++e) {
        unsigned int u = __float_as_uint(xs[e]);
        unsigned short hh = (unsigned short)(u >> 16);
        h[e] = (short)hh;
        l[e] = (short)bf16r(xs[e] - bf16f(hh));
    }
}

// ============ Prep: split f32 array into hi/lo bf16 planes (8 elems/thread) =========
__global__ void k_prep(const float* __restrict__ in,
                       unsigned short* __restrict__ hi,
                       unsigned short* __restrict__ lo,
                       int n8)
{
    const int i = blockIdx.x * 256 + threadIdx.x;
    if (i >= n8) return;
    const float4* p = (const float4*)(in + (size_t)i * 8);
    s16x8 h, l;
    split8r(p[0], p[1], h, l);
    *(s16x8*)(hi + (size_t)i * 8) = h;
    *(s16x8*)(lo + (size_t)i * 8) = l;
}

// ============ Kernel A: bf16-split MFMA GEMM1 + MFMA VQ screen =====================
// Tile 128x256, nt 0..3, BK=32. 8 waves = 4 wm x 2 wn; per wave 2mf x 8nf, 48 MFMA.
// LDS layout: [kc][row][8] u16 chunks with phys_row = row ^ (kc<<2)  (conflict-free).
// u16-chunk index map (chunk = 8 u16 = 16B):
//   Ah: kc*128+p            Al: 512+kc*128+p
//   Bh: 1024+kc*256+p       Bl: 2048+kc*256+p
//   Sh: kc*512+p (alias A/B) Sl: 2048+kc*512+p (alias Bl+)
//   Ch: 4096+kc*256+p       Cl: 5120+kc*256+p
//   cnb: f32 @ u16 49152;   Fv: f32 @ u16 49664
template <bool PREW>
__launch_bounds__(512, 2)
__global__ void k_enc(const float* __restrict__ skills,
                      const float* __restrict__ enc_w,
                      const unsigned short* __restrict__ w_hi,
                      const unsigned short* __restrict__ w_lo,
                      const float* __restrict__ enc_b,
                      const float* __restrict__ cb_g,
                      float* __restrict__ out)
{
    __shared__ __align__(16) unsigned short us[50688];   // 101376 B
    float* cnb = (float*)(us + 49152);
    float* Fv  = (float*)(us + 49664);

    const int tid = threadIdx.x;
    const int r0 = blockIdx.x * 128;
    const int wid = tid >> 6, lane = tid & 63;
    const int wm = wid >> 1, wn = wid & 1;
    const int mbase = wm * 32;
    const int lhi = lane >> 4, llo = lane & 15;
    const int rowA = tid >> 2, kcA = tid & 3;        // A staging
    const int rowB = tid & 255, selB = tid >> 8;     // B staging (selB: kc-pair)

    // ---- stage codebook (swizzled) + cnorm ----
    if (tid < 256) {
        const float4* cr = (const float4*)&cb_g[tid * 32];
        float s = 0.f;
        #pragma unroll
        for (int i = 0; i < 8; ++i) {
            float4 v = cr[i];
            float c[4] = {v.x, v.y, v.z, v.w};
            #pragma unroll
            for (int e = 0; e < 4; ++e) {
                const int d = i * 4 + e, kc = d >> 3, e8 = d & 7;
                const int phys = tid ^ (kc << 2);
                unsigned int u = __float_as_uint(c[e]);
                unsigned short hh = (unsigned short)(u >> 16);
                us[8 * (4096 + kc * 256 + phys) + e8] = hh;
                us[8 * (5120 + kc * 256 + phys) + e8] = bf16r(c[e] - bf16f(hh));
                s = fmaf(c[e], c[e], s);
            }
        }
        cnb[tid] = s;
    }
    __syncthreads();

    float vq_local = 0.f;
    f32x4 acc[2][8];
    float4 pa0, pa1;
    s16x8 pb[4];
    float4 pbf[4];

    // preload it=0 (nt=0, kt=0)
    {
        const float* ap = &skills[(size_t)(r0 + rowA) * 1024 + kcA * 8];
        pa0 = *(const float4*)ap; pa1 = *(const float4*)(ap + 4);
        if (PREW) {
            const unsigned short* wp = (selB ? w_lo : w_hi) + (size_t)rowB * 1024;
            #pragma unroll
            for (int kc = 0; kc < 4; ++kc) pb[kc] = *(const s16x8*)(wp + kc * 8);
        } else {
            const float* bp = &enc_w[(size_t)rowB * 1024 + selB * 16];
            #pragma unroll
            for (int q = 0; q < 4; ++q) pbf[q] = ((const float4*)bp)[q];
        }
    }

    for (int it = 0; it < 128; ++it) {
        const int nt = it >> 5, kt = it & 31;
        const int n0 = nt * 256;
        if (kt == 0) {
            #pragma unroll
            for (int mf = 0; mf < 2; ++mf)
                #pragma unroll
                for (int nf = 0; nf < 8; ++nf) acc[mf][nf] = (f32x4)0.f;
        }
        __syncthreads();                       // prev readers of A/B/S done
        // stage A (split in-kernel)
        {
            s16x8 h, l; split8r(pa0, pa1, h, l);
            const int phys = rowA ^ (kcA << 2);
            *(s16x8*)(us + 8 * (kcA * 128 + phys)) = h;
            *(s16x8*)(us + 8 * (512 + kcA * 128 + phys)) = l;
        }
        // stage B
        if (PREW) {
            const int base = selB ? 2048 : 1024;
            #pragma unroll
            for (int kc = 0; kc < 4; ++kc) {
                const int phys = rowB ^ (kc << 2);
                *(s16x8*)(us + 8 * (base + kc * 256 + phys)) = pb[kc];
            }
        } else {
            #pragma unroll
            for (int kk = 0; kk < 2; ++kk) {
                const int kc = selB * 2 + kk;
                s16x8 h, l; split8r(pbf[kk * 2], pbf[kk * 2 + 1], h, l);
                const int phys = rowB ^ (kc << 2);
                *(s16x8*)(us + 8 * (1024 + kc * 256 + phys)) = h;
                *(s16x8*)(us + 8 * (2048 + kc * 256 + phys)) = l;
            }
        }
        __syncthreads();
        // prefetch it+1 (lands under MFMA / screen)
        if (it < 127) {
            const int it2 = it + 1, nt2 = it2 >> 5, kt2 = it2 & 31;
            const float* ap = &skills[(size_t)(r0 + rowA) * 1024 + kt2 * 32 + kcA * 8];
            pa0 = *(const float4*)ap; pa1 = *(const float4*)(ap + 4);
            if (PREW) {
                const unsigned short* wp = (selB ? w_lo : w_hi)
                    + (size_t)(nt2 * 256 + rowB) * 1024 + kt2 * 32;
                #pragma unroll
                for (int kc = 0; kc < 4; ++kc) pb[kc] = *(const s16x8*)(wp + kc * 8);
            } else {
                const float* bp = &enc_w[(size_t)(nt2 * 256 + rowB) * 1024 + kt2 * 32 + selB * 16];
                #pragma unroll
                for (int q = 0; q < 4; ++q) pbf[q] = ((const float4*)bp)[q];
            }
        }
        // fragments + 3-pass MFMA (order hh,hl,lh per acc, kt ascending)
        {
            s16x8 ah[2], al[2];
            #pragma unroll
            for (int mf = 0; mf < 2; ++mf) {
                const int phys = (mbase + mf * 16 + llo) ^ (lhi << 2);
                ah[mf] = *(s16x8*)(us + 8 * (lhi * 128 + phys));
                al[mf] = *(s16x8*)(us + 8 * (512 + lhi * 128 + phys));
            }
            #pragma unroll
            for (int nf = 0; nf < 8; ++nf) {
                const int phys = (wn * 128 + nf * 16 + llo) ^ (lhi << 2);
                s16x8 bh = *(s16x8*)(us + 8 * (1024 + lhi * 256 + phys));
                s16x8 bl = *(s16x8*)(us + 8 * (2048 + lhi * 256 + phys));
                #pragma unroll
                for (int mf = 0; mf < 2; ++mf) {
                    acc[mf][nf] = __builtin_amdgcn_mfma_f32_16x16x32_bf16(ah[mf], bh, acc[mf][nf], 0, 0, 0);
                    acc[mf][nf] = __builtin_amdgcn_mfma_f32_16x16x32_bf16(ah[mf], bl, acc[mf][nf], 0, 0, 0);
                    acc[mf][nf] = __builtin_amdgcn_mfma_f32_16x16x32_bf16(al[mf], bh, acc[mf][nf], 0, 0, 0);
                }
            }
        }

        if (kt == 31) {
            // screen the 256-wide tile in two 128-col halves (512 tokens each)
            for (int h = 0; h < 2; ++h) {
                __syncthreads();               // GEMM/screen reads done before stash clobbers
                if (wn == h) {
                    float fp[2][4][4];
                    #pragma unroll
                    for (int mf = 0; mf < 2; ++mf)
                        #pragma unroll
                        for (int r = 0; r < 4; ++r)
                            #pragma unroll
                            for (int tl = 0; tl < 4; ++tl) fp[mf][r][tl] = 0.f;
                    #pragma unroll
                    for (int mf = 0; mf < 2; ++mf)
                        #pragma unroll
                        for (int nf = 0; nf < 8; ++nf) {
                            const int col = nf * 16 + llo;
                            const int tl = col >> 5, d = col & 31, kc = d >> 3, e8 = d & 7;
                            const float bias = enc_b[n0 + h * 128 + col];
                            #pragma unroll
                            for (int r = 0; r < 4; ++r) {
                                const int m_local = mbase + mf * 16 + lhi * 4 + r;
                                float val = acc[mf][nf][r] + bias;
                                unsigned int u = __float_as_uint(val);
                                unsigned short hh = (unsigned short)(u >> 16);
                                const int tokr = m_local * 4 + tl;
                                const int phys = tokr ^ (kc << 2);
                                us[8 * (kc * 512 + phys) + e8] = hh;
                                us[8 * (2048 + kc * 512 + phys) + e8] = bf16r(val - bf16f(hh));
                                fp[mf][r][tl] = fmaf(val, val, fp[mf][r][tl]);
                            }
                        }
                    #pragma unroll
                    for (int mf = 0; mf < 2; ++mf)
                        #pragma unroll
                        for (int r = 0; r < 4; ++r)
                            #pragma unroll
                            for (int tl = 0; tl < 4; ++tl) {
                                float f = fp[mf][r][tl];
                                f += __shfl_xor(f, 1); f += __shfl_xor(f, 2);
                                f += __shfl_xor(f, 4); f += __shfl_xor(f, 8);
                                if (llo == 0)
                                    Fv[(mbase + mf * 16 + lhi * 4 + r) * 4 + tl] = f;
                            }
                }
                __syncthreads();
                // ---- screen: jb-outer, 4 token-groups per wave ----
                s16x8 fh[4], fl[4];
                #pragma unroll
                for (int gi = 0; gi < 4; ++gi) {
                    const int tokr = (wid * 4 + gi) * 16 + llo;
                    const int phys = tokr ^ (lhi << 2);
                    fh[gi] = *(s16x8*)(us + 8 * (lhi * 512 + phys));
                    fl[gi] = *(s16x8*)(us + 8 * (2048 + lhi * 512 + phys));
                }
                float s1[4][4], s2[4][4]; int bj[4][4];
                #pragma unroll
                for (int gi = 0; gi < 4; ++gi)
                    #pragma unroll
                    for (int r = 0; r < 4; ++r) { s1[gi][r] = FLT_MAX; s2[gi][r] = FLT_MAX; bj[gi][r] = 0; }
                for (int jb = 0; jb < 16; ++jb) {
                    const int physj = (jb * 16 + llo) ^ (lhi << 2);
                    s16x8 ch = *(s16x8*)(us + 8 * (4096 + lhi * 256 + physj));
                    s16x8 cl = *(s16x8*)(us + 8 * (5120 + lhi * 256 + physj));
                    const float cnv = cnb[jb * 16 + llo];
                    #pragma unroll
                    for (int gi = 0; gi < 4; ++gi) {
                        f32x4 sc = (f32x4)0.f;
                        sc = __builtin_amdgcn_mfma_f32_16x16x32_bf16(fh[gi], ch, sc, 0, 0, 0);
                        sc = __builtin_amdgcn_mfma_f32_16x16x32_bf16(fh[gi], cl, sc, 0, 0, 0);
                        sc = __builtin_amdgcn_mfma_f32_16x16x32_bf16(fl[gi], ch, sc, 0, 0, 0);
                        #pragma unroll
                        for (int r = 0; r < 4; ++r) {
                            float s = fmaf(-2.f, sc[r], cnv);
                            if (s < s1[gi][r])      { s2[gi][r] = s1[gi][r]; s1[gi][r] = s; bj[gi][r] = jb * 16 + llo; }
                            else if (s < s2[gi][r]) { s2[gi][r] = s; }
                        }
                    }
                }
                #pragma unroll
                for (int gi = 0; gi < 4; ++gi)
                    #pragma unroll
                    for (int r = 0; r < 4; ++r) {
                        float a1 = s1[gi][r], a2 = s2[gi][r]; int aj = bj[gi][r];
                        #pragma unroll
                        for (int off = 1; off <= 8; off <<= 1) {
                            float o1 = __shfl_xor(a1, off);
                            float o2 = __shfl_xor(a2, off);
                            int   oj = __shfl_xor(aj, off);
                            if (o1 < a1) { a2 = fminf(a1, o2); a1 = o1; aj = oj; }
                            else         { a2 = fminf(o1, a2); }
                        }
                        if (llo == 0) {
                            const int tok_local = (wid * 4 + gi) * 16 + lhi * 4 + r;
                            const float F = Fv[tok_local];
                            float cv = (a2 - a1 < TAU) ? (float)(aj + 512) : (float)aj;
                            const size_t tok = (size_t)(r0 + (tok_local >> 2)) * 32
                                               + nt * 8 + h * 4 + (tok_local & 3);
                            out[OUT_CODES_OFF + tok] = cv;
                            vq_local += F + a1;
                        }
                    }
            }
        }
    }
    // vq loss partial (pre-scaled)
    {
        float v = vq_local;
        #pragma unroll
        for (int off = 32; off >= 1; off >>= 1) v += __shfl_xor(v, off);
        if (lane == 0) atomicAdd(&out[OUT_LOSS_OFF], v * (1.25f * INV_N));
    }
}

// ============ Kernel F: wave-cooperative faithful numpy-f32 fixup (bit-identical) ===
__launch_bounds__(256)
__global__ void k_fix(const float* __restrict__ skills,
                      const float* __restrict__ enc_w,
                      const float* __restrict__ enc_b,
                      const float* __restrict__ cb_g,
                      float* __restrict__ codes)
{
    __shared__ unsigned int cnt;
    __shared__ unsigned short list[256];

    const int tid = threadIdx.x;
    const int base = blockIdx.x * 256;

    if (tid == 0) cnt = 0;
    __syncthreads();
    {
        const int c = (int)codes[base + tid];
        if (c >= 512) {
            unsigned int ix = atomicAdd(&cnt, 1u);
            list[ix] = (unsigned short)tid;
        }
    }
    __syncthreads();
    const unsigned int n = cnt;
    if (n == 0) return;

    const int wv = tid >> 6, lane = tid & 63;
    const int d = lane & 31;

    for (unsigned int i = wv; i < n; i += 4) {
        const int tok = base + (int)list[i];
        const int row = tok >> 5;
        const int t   = tok & 31;

        const float4* s4 = (const float4*)&skills[(size_t)row * 1024];
        const float4* w4 = (const float4*)&enc_w[(size_t)(t * 32 + d) * 1024];
        float v1 = 0.f, v2 = 0.f, v3 = 0.f;
        for (int q = 0; q < 96; ++q) {
            float4 a = s4[q], b = w4[q];
            v1 = fmaf(a.x, b.x, v1); v1 = fmaf(a.y, b.y, v1);
            v1 = fmaf(a.z, b.z, v1); v1 = fmaf(a.w, b.w, v1);
        }
        for (int q = 96; q < 192; ++q) {
            float4 a = s4[q], b = w4[q];
            v2 = fmaf(a.x, b.x, v2); v2 = fmaf(a.y, b.y, v2);
            v2 = fmaf(a.z, b.z, v2); v2 = fmaf(a.w, b.w, v2);
        }
        for (int q = 192; q < 256; ++q) {
            float4 a = s4[q], b = w4[q];
            v3 = fmaf(a.x, b.x, v3); v3 = fmaf(a.y, b.y, v3);
            v3 = fmaf(a.z, b.z, v3); v3 = fmaf(a.w, b.w, v3);
        }
        const float pd = ((v1 + v2) + v3) + enc_b[t * 32 + d];

        float pv[32];
        #pragma unroll
        for (int dd = 0; dd < 32; ++dd) pv[dd] = __shfl(pd, dd);

        float F;
        {
            float s[32];
            #pragma unroll
            for (int dd = 0; dd < 32; ++dd) s[dd] = pv[dd] * pv[dd];
            float r[8];
            #pragma unroll
            for (int j = 0; j < 8; ++j) r[j] = ((s[j] + s[8+j]) + s[16+j]) + s[24+j];
            F = ((r[0] + r[1]) + (r[2] + r[3])) + ((r[4] + r[5]) + (r[6] + r[7]));
        }

        float bs = FLT_MAX; int bj = 0;
        for (int m = 0; m < 4; ++m) {
            const int j = m * 64 + lane;
            const float* cj = &cb_g[j * 32];
            float g = 0.f;
            #pragma unroll
            for (int dd = 0; dd < 32; ++dd) g = fmaf(pv[dd], cj[dd], g);
            float cs[32];
            #pragma unroll
            for (int dd = 0; dd < 32; ++dd) cs[dd] = cj[dd] * cj[dd];
            float r[8];
            #pragma unroll
            for (int jj = 0; jj < 8; ++jj) r[jj] = ((cs[jj] + cs[8+jj]) + cs[16+jj]) + cs[24+jj];
            float cn = ((r[0] + r[1]) + (r[2] + r[3])) + ((r[4] + r[5]) + (r[6] + r[7]));
            float dist = (F - 2.0f * g) + cn;
            if (dist < bs) { bs = dist; bj = j; }
        }
        #pragma unroll
        for (int off = 32; off >= 1; off >>= 1) {
            float os = __shfl_xor(bs, off);
            int   oj = __shfl_xor(bj, off);
            if (os < bs || (os == bs && oj < bj)) { bs = os; bj = oj; }
        }
        if (lane == 0) codes[tok] = (float)bj;
    }
}

// ============ Kernel B: bf16 MFMA GEMM2 (quantized@dec_w^T + b) + recon loss ========
__launch_bounds__(512)
__global__ void k_dec(const float* __restrict__ skills,
                      const float* __restrict__ cb_g,
                      const float* __restrict__ dec_w,
                      const float* __restrict__ dec_b,
                      const float* __restrict__ codes,
                      float* __restrict__ recon,
                      float* __restrict__ loss_out)
{
    __shared__ unsigned short Qt[128][40], Wt[128][40];

    const int tid = threadIdx.x;
    const int r0 = (blockIdx.x >> 3) * 128;
    const int n0 = (blockIdx.x & 7) * 128;
    const int wid = tid >> 6, lane = tid & 63;
    const int wm = wid >> 1, wn = wid & 1;
    const int mbase = wm * 32, nbase = wn * 64;
    const int lhi = lane >> 4, llo = lane & 15;
    const int srow = tid >> 2, sq = tid & 3;

    f32x4 acc[2][4];
    #pragma unroll
    for (int mf = 0; mf < 2; ++mf)
        #pragma unroll
        for (int nf = 0; nf < 4; ++nf) acc[mf][nf] = (f32x4)0.f;

    float4 q0, q1, w0, w1;
    int cnext;
    {
        const int c0 = ((int)codes[(size_t)(r0 + srow) * 32 + 0]) & 255;
        const float* cp = &cb_g[c0 * 32 + sq * 8];
        q0 = *(const float4*)cp; q1 = *(const float4*)(cp + 4);
        const float* wp = &dec_w[(size_t)(n0 + srow) * 1024 + sq * 8];
        w0 = *(const float4*)wp; w1 = *(const float4*)(wp + 4);
        cnext = ((int)codes[(size_t)(r0 + srow) * 32 + 1]) & 255;
    }

    for (int t = 0; t < 32; ++t) {
        __syncthreads();
        {
            float xs[8] = {q0.x, q0.y, q0.z, q0.w, q1.x, q1.y, q1.z, q1.w};
            s16x8 h;
            #pragma unroll
            for (int e = 0; e < 8; ++e) h[e] = (short)bf16r(xs[e]);
            *(s16x8*)&Qt[srow][sq * 8] = h;
            float ys[8] = {w0.x, w0.y, w0.z, w0.w, w1.x, w1.y, w1.z, w1.w};
            #pragma unroll
            for (int e = 0; e < 8; ++e) h[e] = (short)bf16r(ys[e]);
            *(s16x8*)&Wt[srow][sq * 8] = h;
        }
        __syncthreads();
        if (t < 31) {
            const float* cp = &cb_g[cnext * 32 + sq * 8];
            q0 = *(const float4*)cp; q1 = *(const float4*)(cp + 4);
            const float* wp = &dec_w[(size_t)(n0 + srow) * 1024 + (t + 1) * 32 + sq * 8];
            w0 = *(const float4*)wp; w1 = *(const float4*)(wp + 4);
            if (t < 30) cnext = ((int)codes[(size_t)(r0 + srow) * 32 + t + 2]) & 255;
        }
        s16x8 aq[2], bw[4];
        #pragma unroll
        for (int mf = 0; mf < 2; ++mf)
            aq[mf] = *(s16x8*)&Qt[mbase + mf * 16 + llo][lhi * 8];
        #pragma unroll
        for (int nf = 0; nf < 4; ++nf)
            bw[nf] = *(s16x8*)&Wt[nbase + nf * 16 + llo][lhi * 8];
        #pragma unroll
        for (int mf = 0; mf < 2; ++mf)
            #pragma unroll
            for (int nf = 0; nf < 4; ++nf)
                acc[mf][nf] = __builtin_amdgcn_mfma_f32_16x16x32_bf16(aq[mf], bw[nf], acc[mf][nf], 0, 0, 0);
    }

    float lsum = 0.f;
    #pragma unroll
    for (int mf = 0; mf < 2; ++mf)
        #pragma unroll
        for (int nf = 0; nf < 4; ++nf) {
            const int col = n0 + nbase + nf * 16 + llo;
            const float bias = dec_b[col];
            #pragma unroll
            for (int r = 0; r < 4; ++r) {
                const int row = r0 + mbase + mf * 16 + lhi * 4 + r;
                float rv = acc[mf][nf][r] + bias;
                float dv = rv - skills[(size_t)row * 1024 + col];
                lsum = fmaf(dv, dv, lsum);
                recon[(size_t)row * 1024 + col] = rv;
            }
        }
    #pragma unroll
    for (int off = 32; off >= 1; off >>= 1) lsum += __shfl_xor(lsum, off);
    if (lane == 0) atomicAdd(loss_out, lsum * INV_N);
}

extern "C" void kernel_launch(void* const* d_in, const int* in_sizes, int n_in,
                              void* d_out, int out_size, void* d_ws, size_t ws_size,
                              hipStream_t stream)
{
    const float* skills = (const float*)d_in[0];
    const float* enc_w  = (const float*)d_in[1];
    const float* enc_b  = (const float*)d_in[2];
    const float* cbg    = (const float*)d_in[3];
    const float* dec_w  = (const float*)d_in[4];
    const float* dec_b  = (const float*)d_in[5];
    float* out = (float*)d_out;

    hipMemsetAsync(out + OUT_LOSS_OFF, 0, 4, stream);

    const bool prew = (ws_size >= (4UL * 1048576UL + 64UL));
    unsigned short* w_hi = (unsigned short*)d_ws;
    unsigned short* w_lo = w_hi + 1048576UL;
    if (prew) {
        k_prep<<<dim3(512), dim3(256), 0, stream>>>(enc_w, w_hi, w_lo, 131072);
        k_enc<true><<<dim3(256), dim3(512), 0, stream>>>(skills, enc_w, w_hi, w_lo,
                                                         enc_b, cbg, out);
    } else {
        k_enc<false><<<dim3(256), dim3(512), 0, stream>>>(skills, enc_w, w_hi, w_lo,
                                                          enc_b, cbg, out);
    }
    k_fix<<<dim3(4096), dim3(256), 0, stream>>>(skills, enc_w, enc_b, cbg, out + OUT_CODES_OFF);
    k_dec<<<dim3(2048), dim3(512), 0, stream>>>(skills, cbg, dec_w, dec_b,
                                                out + OUT_CODES_OFF, out, out + OUT_LOSS_OFF);
}

// Round 11
// 918.247 us; speedup vs baseline: 2.4411x; 2.4411x over previous
//
#include <hip/hip_runtime.h>
#include <hip/hip_bf16.h>
#include <float.h>

#define OUT_CODES_OFF (33554432UL)            // 32768*1024
#define OUT_LOSS_OFF  (34603008UL)            // + 32768*32
#define TAU 1e-5f
#define INV_N (1.0f/33554432.0f)

typedef __attribute__((ext_vector_type(8))) short s16x8;
typedef __attribute__((ext_vector_type(4))) float f32x4;

__device__ __forceinline__ unsigned short bf16r(float x) {
    unsigned int u = __float_as_uint(x);
    unsigned int r = (u + 0x7FFFu + ((u >> 16) & 1u)) >> 16;
    return (unsigned short)r;
}
__device__ __forceinline__ float bf16f(unsigned short h) {
    return __uint_as_float(((unsigned int)h) << 16);
}
// truncation split: x = hi + lo with hi = trunc-bf16(x), lo = rnd-bf16(x - hi)
__device__ __forceinline__ void split8r(float4 v0, float4 v1, s16x8& h, s16x8& l) {
    float xs[8] = {v0.x, v0.y, v0.z, v0.w, v1.x, v1.y, v1.z, v1.w};
    #pragma unroll
    for (int e = 0; e < 8; ++e) {
        unsigned int u = __float_as_uint(xs[e]);
        unsigned short hh = (unsigned short)(u >> 16);
        h[e] = (short)hh;
        l[e] = (short)bf16r(xs[e] - bf16f(hh));
    }
}

// ============ Prep: round f32 array to bf16 (rnd-to-nearest-even), 8 elems/thread ===
__global__ void k_prep_r(const float* __restrict__ in,
                         unsigned short* __restrict__ o,
                         int n8)
{
    const int i = blockIdx.x * 256 + threadIdx.x;
    if (i >= n8) return;
    const float4* p = (const float4*)(in + (size_t)i * 8);
    float4 v0 = p[0], v1 = p[1];
    float xs[8] = {v0.x, v0.y, v0.z, v0.w, v1.x, v1.y, v1.z, v1.w};
    s16x8 h;
    #pragma unroll
    for (int e = 0; e < 8; ++e) h[e] = (short)bf16r(xs[e]);
    *(s16x8*)(o + (size_t)i * 8) = h;
}

// ============ Kernel A: bf16-split MFMA GEMM1 + MFMA VQ screen (round-7, proven) ====
// grid 256 x 512thr (8 waves, 4Mx2N). BM=128, 8 n-tiles of BN=128, BK=32.
// Flattened (nt,kt) loop with register prefetch; stash aliases A/B LDS.
__launch_bounds__(512, 1)
__global__ void k_enc(const float* __restrict__ skills,
                      const float* __restrict__ enc_w,
                      const float* __restrict__ enc_b,
                      const float* __restrict__ cb_g,
                      float* __restrict__ out)
{
    __shared__ __align__(16) char smem[125952];
    typedef unsigned short (*pu40)[40];
    pu40 Ah = (pu40)(smem);                 // [128][40]
    pu40 Al = (pu40)(smem + 10240);
    pu40 Bh = (pu40)(smem + 20480);
    pu40 Bl = (pu40)(smem + 30720);
    pu40 Sh = (pu40)(smem);                 // [512][40] alias over A/B (disjoint in time)
    pu40 Sl = (pu40)(smem + 40960);
    pu40 Ch = (pu40)(smem + 81920);         // [256][40]
    pu40 Cl = (pu40)(smem + 102400);
    float* cnb = (float*)(smem + 122880);   // [256]
    float* Fv  = (float*)(smem + 123904);   // [512]

    const int tid = threadIdx.x;
    const int r0 = blockIdx.x * 128;
    const int wid = tid >> 6, lane = tid & 63;
    const int wm = wid >> 1, wn = wid & 1;
    const int mbase = wm * 32, nbase = wn * 64;
    const int lhi = lane >> 4, llo = lane & 15;
    const int srow = tid >> 2, sq = tid & 3;

    // ---- stage codebook split + cnorm ----
    if (tid < 256) {
        const float4* cr = (const float4*)&cb_g[tid * 32];
        float s = 0.f;
        #pragma unroll
        for (int i = 0; i < 8; ++i) {
            float4 v = cr[i];
            float c[4] = {v.x, v.y, v.z, v.w};
            #pragma unroll
            for (int e = 0; e < 4; ++e) {
                unsigned int u = __float_as_uint(c[e]);
                unsigned short hh = (unsigned short)(u >> 16);
                Ch[tid][i*4+e] = hh;
                Cl[tid][i*4+e] = bf16r(c[e] - bf16f(hh));
                s = fmaf(c[e], c[e], s);
            }
        }
        cnb[tid] = s;
    }
    __syncthreads();

    float vq_local = 0.f;
    f32x4 acc[2][4];
    float4 ra0, ra1, rb0, rb1;

    // preload it=0 (nt=0, kt=0)
    {
        const float* ap = &skills[(size_t)(r0 + srow) * 1024 + sq * 8];
        ra0 = *(const float4*)ap; ra1 = *(const float4*)(ap + 4);
        const float* bp = &enc_w[(size_t)srow * 1024 + sq * 8];
        rb0 = *(const float4*)bp; rb1 = *(const float4*)(bp + 4);
    }

    for (int it = 0; it < 256; ++it) {
        const int nt = it >> 5, kt = it & 31;
        const int n0 = nt * 128;
        if (kt == 0) {
            #pragma unroll
            for (int mf = 0; mf < 2; ++mf)
                #pragma unroll
                for (int nf = 0; nf < 4; ++nf) acc[mf][nf] = (f32x4)0.f;
        }
        __syncthreads();                       // prev readers of A/B (or S) done
        {
            s16x8 h, l;
            split8r(ra0, ra1, h, l);
            *(s16x8*)&Ah[srow][sq * 8] = h;
            *(s16x8*)&Al[srow][sq * 8] = l;
            split8r(rb0, rb1, h, l);
            *(s16x8*)&Bh[srow][sq * 8] = h;
            *(s16x8*)&Bl[srow][sq * 8] = l;
        }
        __syncthreads();
        // prefetch it+1 (hidden under MFMA / screen)
        if (it < 255) {
            const int it2 = it + 1, nt2 = it2 >> 5, kt2 = it2 & 31;
            const float* ap = &skills[(size_t)(r0 + srow) * 1024 + kt2 * 32 + sq * 8];
            ra0 = *(const float4*)ap; ra1 = *(const float4*)(ap + 4);
            const float* bp = &enc_w[(size_t)(nt2 * 128 + srow) * 1024 + kt2 * 32 + sq * 8];
            rb0 = *(const float4*)bp; rb1 = *(const float4*)(bp + 4);
        }
        // fragments + 3-pass MFMA
        {
            s16x8 ah[2], al[2], bh[4], bl[4];
            #pragma unroll
            for (int mf = 0; mf < 2; ++mf) {
                const int row = mbase + mf * 16 + llo;
                ah[mf] = *(s16x8*)&Ah[row][lhi * 8];
                al[mf] = *(s16x8*)&Al[row][lhi * 8];
            }
            #pragma unroll
            for (int nf = 0; nf < 4; ++nf) {
                const int row = nbase + nf * 16 + llo;
                bh[nf] = *(s16x8*)&Bh[row][lhi * 8];
                bl[nf] = *(s16x8*)&Bl[row][lhi * 8];
            }
            #pragma unroll
            for (int mf = 0; mf < 2; ++mf)
                #pragma unroll
                for (int nf = 0; nf < 4; ++nf) {
                    acc[mf][nf] = __builtin_amdgcn_mfma_f32_16x16x32_bf16(ah[mf], bh[nf], acc[mf][nf], 0, 0, 0);
                    acc[mf][nf] = __builtin_amdgcn_mfma_f32_16x16x32_bf16(ah[mf], bl[nf], acc[mf][nf], 0, 0, 0);
                    acc[mf][nf] = __builtin_amdgcn_mfma_f32_16x16x32_bf16(al[mf], bh[nf], acc[mf][nf], 0, 0, 0);
                }
        }

        if (kt == 31) {
            __syncthreads();                   // MFMA frag reads done -> stash may clobber A/B
            // ---- bias + stash (bf16 trunc-split) + F partials ----
            float fp[2][4][2];
            #pragma unroll
            for (int mf = 0; mf < 2; ++mf)
                #pragma unroll
                for (int r = 0; r < 4; ++r) { fp[mf][r][0] = 0.f; fp[mf][r][1] = 0.f; }

            #pragma unroll
            for (int mf = 0; mf < 2; ++mf)
                #pragma unroll
                for (int nf = 0; nf < 4; ++nf) {
                    const int n_local = nbase + nf * 16 + llo;
                    const float bias = enc_b[n0 + n_local];
                    const int tl = wn * 2 + (nf >> 1);
                    const int d = ((nf & 1) << 4) + llo;
                    #pragma unroll
                    for (int r = 0; r < 4; ++r) {
                        const int m_local = mbase + mf * 16 + lhi * 4 + r;
                        float val = acc[mf][nf][r] + bias;
                        unsigned int u = __float_as_uint(val);
                        unsigned short hh = (unsigned short)(u >> 16);
                        Sh[m_local * 4 + tl][d] = hh;
                        Sl[m_local * 4 + tl][d] = bf16r(val - bf16f(hh));
                        fp[mf][r][nf >> 1] = fmaf(val, val, fp[mf][r][nf >> 1]);
                    }
                }
            #pragma unroll
            for (int mf = 0; mf < 2; ++mf)
                #pragma unroll
                for (int r = 0; r < 4; ++r)
                    #pragma unroll
                    for (int tt = 0; tt < 2; ++tt) {
                        float f = fp[mf][r][tt];
                        f += __shfl_xor(f, 1); f += __shfl_xor(f, 2);
                        f += __shfl_xor(f, 4); f += __shfl_xor(f, 8);
                        if (llo == 0)
                            Fv[(mbase + mf * 16 + lhi * 4 + r) * 4 + wn * 2 + tt] = f;
                    }
            __syncthreads();

            // ---- MFMA score screen: 4 token-groups of 16 per wave ----
            #pragma unroll
            for (int gi = 0; gi < 4; ++gi) {
                const int g = wid * 4 + gi;
                const int tokrow = g * 16 + llo;
                s16x8 fh = *(s16x8*)&Sh[tokrow][lhi * 8];
                s16x8 fl = *(s16x8*)&Sl[tokrow][lhi * 8];
                float s1[4], s2[4]; int bj[4];
                #pragma unroll
                for (int r = 0; r < 4; ++r) { s1[r] = FLT_MAX; s2[r] = FLT_MAX; bj[r] = 0; }
                for (int jb = 0; jb < 16; ++jb) {
                    const int j = jb * 16 + llo;
                    s16x8 ch = *(s16x8*)&Ch[j][lhi * 8];
                    s16x8 cl = *(s16x8*)&Cl[j][lhi * 8];
                    f32x4 sc = (f32x4)0.f;
                    sc = __builtin_amdgcn_mfma_f32_16x16x32_bf16(fh, ch, sc, 0, 0, 0);
                    sc = __builtin_amdgcn_mfma_f32_16x16x32_bf16(fh, cl, sc, 0, 0, 0);
                    sc = __builtin_amdgcn_mfma_f32_16x16x32_bf16(fl, ch, sc, 0, 0, 0);
                    const float cnv = cnb[j];
                    #pragma unroll
                    for (int r = 0; r < 4; ++r) {
                        float s = fmaf(-2.f, sc[r], cnv);
                        if (s < s1[r])      { s2[r] = s1[r]; s1[r] = s; bj[r] = j; }
                        else if (s < s2[r]) { s2[r] = s; }
                    }
                }
                #pragma unroll
                for (int r = 0; r < 4; ++r) {
                    float a1 = s1[r], a2 = s2[r]; int aj = bj[r];
                    #pragma unroll
                    for (int off = 1; off <= 8; off <<= 1) {
                        float o1 = __shfl_xor(a1, off);
                        float o2 = __shfl_xor(a2, off);
                        int   oj = __shfl_xor(aj, off);
                        if (o1 < a1) { a2 = fminf(a1, o2); a1 = o1; aj = oj; }
                        else         { a2 = fminf(o1, a2); }
                    }
                    if (llo == 0) {
                        const int tok_local = g * 16 + lhi * 4 + r;
                        const float F = Fv[tok_local];
                        float cv = (a2 - a1 < TAU) ? (float)(aj + 512) : (float)aj;
                        const size_t tok = (size_t)(r0 + (tok_local >> 2)) * 32 + nt * 4 + (tok_local & 3);
                        out[OUT_CODES_OFF + tok] = cv;
                        vq_local += F + a1;
                    }
                }
            }
        }
    }
    // vq loss partial (pre-scaled)
    {
        float v = vq_local;
        #pragma unroll
        for (int off = 32; off >= 1; off >>= 1) v += __shfl_xor(v, off);
        if (lane == 0) atomicAdd(&out[OUT_LOSS_OFF], v * (1.25f * INV_N));
    }
}

// ============ Kernel F: wave-cooperative faithful numpy-f32 fixup (bit-identical) ===
__launch_bounds__(256)
__global__ void k_fix(const float* __restrict__ skills,
                      const float* __restrict__ enc_w,
                      const float* __restrict__ enc_b,
                      const float* __restrict__ cb_g,
                      float* __restrict__ codes)
{
    __shared__ unsigned int cnt;
    __shared__ unsigned short list[256];

    const int tid = threadIdx.x;
    const int base = blockIdx.x * 256;

    if (tid == 0) cnt = 0;
    __syncthreads();
    {
        const int c = (int)codes[base + tid];
        if (c >= 512) {
            unsigned int ix = atomicAdd(&cnt, 1u);
            list[ix] = (unsigned short)tid;
        }
    }
    __syncthreads();
    const unsigned int n = cnt;
    if (n == 0) return;

    const int wv = tid >> 6, lane = tid & 63;
    const int d = lane & 31;

    for (unsigned int i = wv; i < n; i += 4) {
        const int tok = base + (int)list[i];
        const int row = tok >> 5;
        const int t   = tok & 31;

        const float4* s4 = (const float4*)&skills[(size_t)row * 1024];
        const float4* w4 = (const float4*)&enc_w[(size_t)(t * 32 + d) * 1024];
        float v1 = 0.f, v2 = 0.f, v3 = 0.f;
        for (int q = 0; q < 96; ++q) {
            float4 a = s4[q], b = w4[q];
            v1 = fmaf(a.x, b.x, v1); v1 = fmaf(a.y, b.y, v1);
            v1 = fmaf(a.z, b.z, v1); v1 = fmaf(a.w, b.w, v1);
        }
        for (int q = 96; q < 192; ++q) {
            float4 a = s4[q], b = w4[q];
            v2 = fmaf(a.x, b.x, v2); v2 = fmaf(a.y, b.y, v2);
            v2 = fmaf(a.z, b.z, v2); v2 = fmaf(a.w, b.w, v2);
        }
        for (int q = 192; q < 256; ++q) {
            float4 a = s4[q], b = w4[q];
            v3 = fmaf(a.x, b.x, v3); v3 = fmaf(a.y, b.y, v3);
            v3 = fmaf(a.z, b.z, v3); v3 = fmaf(a.w, b.w, v3);
        }
        const float pd = ((v1 + v2) + v3) + enc_b[t * 32 + d];

        float pv[32];
        #pragma unroll
        for (int dd = 0; dd < 32; ++dd) pv[dd] = __shfl(pd, dd);

        float F;
        {
            float s[32];
            #pragma unroll
            for (int dd = 0; dd < 32; ++dd) s[dd] = pv[dd] * pv[dd];
            float r[8];
            #pragma unroll
            for (int j = 0; j < 8; ++j) r[j] = ((s[j] + s[8+j]) + s[16+j]) + s[24+j];
            F = ((r[0] + r[1]) + (r[2] + r[3])) + ((r[4] + r[5]) + (r[6] + r[7]));
        }

        float bs = FLT_MAX; int bj = 0;
        for (int m = 0; m < 4; ++m) {
            const int j = m * 64 + lane;
            const float* cj = &cb_g[j * 32];
            float g = 0.f;
            #pragma unroll
            for (int dd = 0; dd < 32; ++dd) g = fmaf(pv[dd], cj[dd], g);
            float cs[32];
            #pragma unroll
            for (int dd = 0; dd < 32; ++dd) cs[dd] = cj[dd] * cj[dd];
            float r[8];
            #pragma unroll
            for (int jj = 0; jj < 8; ++jj) r[jj] = ((cs[jj] + cs[8+jj]) + cs[16+jj]) + cs[24+jj];
            float cn = ((r[0] + r[1]) + (r[2] + r[3])) + ((r[4] + r[5]) + (r[6] + r[7]));
            float dist = (F - 2.0f * g) + cn;
            if (dist < bs) { bs = dist; bj = j; }
        }
        #pragma unroll
        for (int off = 32; off >= 1; off >>= 1) {
            float os = __shfl_xor(bs, off);
            int   oj = __shfl_xor(bj, off);
            if (os < bs || (os == bs && oj < bj)) { bs = os; bj = oj; }
        }
        if (lane == 0) codes[tok] = (float)bj;
    }
}

// ============ Kernel B: bf16 MFMA GEMM2 (quantized@dec_w^T + b) + recon loss ========
// PRED: dec_w and codebook pre-rounded to bf16 in ws -> staging is pure u16 copy.
template <bool PRED>
__launch_bounds__(512)
__global__ void k_dec(const float* __restrict__ skills,
                      const float* __restrict__ cb_g,
                      const unsigned short* __restrict__ cbb,
                      const float* __restrict__ dec_w,
                      const unsigned short* __restrict__ dwb,
                      const float* __restrict__ dec_b,
                      const float* __restrict__ codes,
                      float* __restrict__ recon,
                      float* __restrict__ loss_out)
{
    __shared__ unsigned short Qt[128][40], Wt[128][40];

    const int tid = threadIdx.x;
    const int r0 = (blockIdx.x >> 3) * 128;
    const int n0 = (blockIdx.x & 7) * 128;
    const int wid = tid >> 6, lane = tid & 63;
    const int wm = wid >> 1, wn = wid & 1;
    const int mbase = wm * 32, nbase = wn * 64;
    const int lhi = lane >> 4, llo = lane & 15;
    const int srow = tid >> 2, sq = tid & 3;

    f32x4 acc[2][4];
    #pragma unroll
    for (int mf = 0; mf < 2; ++mf)
        #pragma unroll
        for (int nf = 0; nf < 4; ++nf) acc[mf][nf] = (f32x4)0.f;

    s16x8 q16, w16;
    float4 q0, q1, w0, w1;
    int cnext;
    {
        const int c0 = ((int)codes[(size_t)(r0 + srow) * 32 + 0]) & 255;
        if (PRED) {
            q16 = *(const s16x8*)(cbb + c0 * 32 + sq * 8);
            w16 = *(const s16x8*)(dwb + (size_t)(n0 + srow) * 1024 + sq * 8);
        } else {
            const float* cp = &cb_g[c0 * 32 + sq * 8];
            q0 = *(const float4*)cp; q1 = *(const float4*)(cp + 4);
            const float* wp = &dec_w[(size_t)(n0 + srow) * 1024 + sq * 8];
            w0 = *(const float4*)wp; w1 = *(const float4*)(wp + 4);
        }
        cnext = ((int)codes[(size_t)(r0 + srow) * 32 + 1]) & 255;
    }

    for (int t = 0; t < 32; ++t) {
        __syncthreads();
        if (PRED) {
            *(s16x8*)&Qt[srow][sq * 8] = q16;
            *(s16x8*)&Wt[srow][sq * 8] = w16;
        } else {
            float xs[8] = {q0.x, q0.y, q0.z, q0.w, q1.x, q1.y, q1.z, q1.w};
            s16x8 h;
            #pragma unroll
            for (int e = 0; e < 8; ++e) h[e] = (short)bf16r(xs[e]);
            *(s16x8*)&Qt[srow][sq * 8] = h;
            float ys[8] = {w0.x, w0.y, w0.z, w0.w, w1.x, w1.y, w1.z, w1.w};
            #pragma unroll
            for (int e = 0; e < 8; ++e) h[e] = (short)bf16r(ys[e]);
            *(s16x8*)&Wt[srow][sq * 8] = h;
        }
        __syncthreads();
        if (t < 31) {
            if (PRED) {
                q16 = *(const s16x8*)(cbb + cnext * 32 + sq * 8);
                w16 = *(const s16x8*)(dwb + (size_t)(n0 + srow) * 1024 + (t + 1) * 32 + sq * 8);
            } else {
                const float* cp = &cb_g[cnext * 32 + sq * 8];
                q0 = *(const float4*)cp; q1 = *(const float4*)(cp + 4);
                const float* wp = &dec_w[(size_t)(n0 + srow) * 1024 + (t + 1) * 32 + sq * 8];
                w0 = *(const float4*)wp; w1 = *(const float4*)(wp + 4);
            }
            if (t < 30) cnext = ((int)codes[(size_t)(r0 + srow) * 32 + t + 2]) & 255;
        }
        s16x8 aq[2], bw[4];
        #pragma unroll
        for (int mf = 0; mf < 2; ++mf)
            aq[mf] = *(s16x8*)&Qt[mbase + mf * 16 + llo][lhi * 8];
        #pragma unroll
        for (int nf = 0; nf < 4; ++nf)
            bw[nf] = *(s16x8*)&Wt[nbase + nf * 16 + llo][lhi * 8];
        #pragma unroll
        for (int mf = 0; mf < 2; ++mf)
            #pragma unroll
            for (int nf = 0; nf < 4; ++nf)
                acc[mf][nf] = __builtin_amdgcn_mfma_f32_16x16x32_bf16(aq[mf], bw[nf], acc[mf][nf], 0, 0, 0);
    }

    float lsum = 0.f;
    #pragma unroll
    for (int mf = 0; mf < 2; ++mf)
        #pragma unroll
        for (int nf = 0; nf < 4; ++nf) {
            const int col = n0 + nbase + nf * 16 + llo;
            const float bias = dec_b[col];
            #pragma unroll
            for (int r = 0; r < 4; ++r) {
                const int row = r0 + mbase + mf * 16 + lhi * 4 + r;
                float rv = acc[mf][nf][r] + bias;
                float dv = rv - skills[(size_t)row * 1024 + col];
                lsum = fmaf(dv, dv, lsum);
                recon[(size_t)row * 1024 + col] = rv;
            }
        }
    #pragma unroll
    for (int off = 32; off >= 1; off >>= 1) lsum += __shfl_xor(lsum, off);
    if (lane == 0) atomicAdd(loss_out, lsum * INV_N);
}

extern "C" void kernel_launch(void* const* d_in, const int* in_sizes, int n_in,
                              void* d_out, int out_size, void* d_ws, size_t ws_size,
                              hipStream_t stream)
{
    const float* skills = (const float*)d_in[0];
    const float* enc_w  = (const float*)d_in[1];
    const float* enc_b  = (const float*)d_in[2];
    const float* cbg    = (const float*)d_in[3];
    const float* dec_w  = (const float*)d_in[4];
    const float* dec_b  = (const float*)d_in[5];
    float* out = (float*)d_out;

    hipMemsetAsync(out + OUT_LOSS_OFF, 0, 4, stream);
    k_enc<<<dim3(256), dim3(512), 0, stream>>>(skills, enc_w, enc_b, cbg, out);
    k_fix<<<dim3(4096), dim3(256), 0, stream>>>(skills, enc_w, enc_b, cbg, out + OUT_CODES_OFF);

    // dec_w bf16 (2 MB) + codebook bf16 (16 KB) in ws, if it fits
    const bool pred = (ws_size >= (2097152UL + 16384UL + 64UL));
    unsigned short* dwb = (unsigned short*)d_ws;
    unsigned short* cbb = dwb + 1048576UL;
    if (pred) {
        k_prep_r<<<dim3(512), dim3(256), 0, stream>>>(dec_w, dwb, 131072);
        k_prep_r<<<dim3(4), dim3(256), 0, stream>>>(cbg, cbb, 1024);
        k_dec<true><<<dim3(2048), dim3(512), 0, stream>>>(skills, cbg, cbb, dec_w, dwb, dec_b,
                                                          out + OUT_CODES_OFF, out, out + OUT_LOSS_OFF);
    } else {
        k_dec<false><<<dim3(2048), dim3(512), 0, stream>>>(skills, cbg, cbb, dec_w, dwb, dec_b,
                                                           out + OUT_CODES_OFF, out, out + OUT_LOSS_OFF);
    }
}